// Round 1
// baseline (414.634 us; speedup 1.0000x reference)
//
#include <hip/hip_runtime.h>
#include <math.h>

#define NS 64
#define INV2PI  0.15915494309189535f
#define NEGHL2E (-0.72134752044448170f)   // -0.5 * log2(e)

// P (3x21) flat row-major, exactly as in the reference.
__constant__ float c_P[63] = {
  0.8506508f, 0.0f, 0.5257311f, 0.809017f, 0.5f, 0.309017f, 0.5257311f,
  0.8506508f, 0.0f, 1.0f, 0.0f, 0.0f, 0.809017f, 0.5f, -0.309017f,
  0.8506508f, 0.0f, -0.5257311f, 0.309017f, 0.809017f, -0.5f,
  0.0f, 0.5257311f, -0.8506508f, 0.5f, 0.309017f, -0.809017f, 0.0f, 1.0f,
  0.0f, -0.5257311f, 0.8506508f, 0.0f, -0.309017f, 0.809017f, -0.5f, 0.0f,
  0.5257311f, 0.8506508f, -0.309017f, 0.809017f, 0.5f,
  0.309017f, 0.809017f, 0.5f, 0.5f, 0.309017f, 0.809017f, 0.5f, -0.309017f,
  0.809017f, 0.0f, 0.0f, 1.0f, -0.5f, 0.309017f, 0.809017f, -0.809017f,
  0.5f, 0.309017f, -0.809017f, 0.5f, -0.309017f
};

struct Moments { float t_mean, t_var, r_var; };

__device__ inline Moments frustum_moments(float t0, float t1, float radius) {
    float mu  = 0.5f * (t0 + t1);
    float hw  = 0.5f * (t1 - t0);
    float mu2 = mu * mu, hw2 = hw * hw;
    float denom = 3.0f * mu2 + hw2;
    float inv_d = 1.0f / denom;
    float hw4 = hw2 * hw2;
    Moments m;
    m.t_mean = mu + 2.0f * mu * hw2 * inv_d;
    m.t_var  = hw2 * (1.0f / 3.0f)
             - (4.0f / 15.0f) * (hw4 * (12.0f * mu2 - hw2) * inv_d * inv_d);
    m.r_var  = radius * radius *
               (0.25f * mu2 + (5.0f / 12.0f) * hw2 - (4.0f / 15.0f) * hw4 * inv_d);
    return m;
}

__global__ __launch_bounds__(256) void mipnerf_enc(
    const float* __restrict__ ray_o,
    const float* __restrict__ ray_d,
    const float* __restrict__ fgz,
    const float* __restrict__ bgz,
    const float* __restrict__ radii,
    float* __restrict__ out)
{
    const int n   = blockIdx.x;
    const int tid = threadIdx.x;

    // Per-sample sources: 24 pairs (X = x/2pi, V = -0.5*log2e * var), stride 50 (odd/2 pad).
    __shared__ float sXV[NS * 50];
    // Per-sample bg core: x0..2, u0..2, g, c1, c2, c3 (stride 11).
    __shared__ float sCore[NS * 11];

    const float ox = ray_o[3 * n + 0], oy = ray_o[3 * n + 1], oz = ray_o[3 * n + 2];
    const float dx = ray_d[3 * n + 0], dy = ray_d[3 * n + 1], dz = ray_d[3 * n + 2];
    const float rad = radii[n];
    const float dm = fmaxf(1e-8f, dx * dx + dy * dy + dz * dz);
    const float inv_dm = 1.0f / dm;

    if (tid < NS) {
        const int s = tid;
        { // ---- FG (diagonal covariance) ----
            float t0 = fgz[(NS + 1) * n + s];
            float t1 = fgz[(NS + 1) * n + s + 1];
            Moments mm = frustum_moments(t0, t1, rad);
            float d3[3] = {dx, dy, dz};
            float o3[3] = {ox, oy, oz};
            #pragma unroll
            for (int i = 0; i < 3; ++i) {
                float m  = o3[i] + d3[i] * mm.t_mean;
                float dd = d3[i] * d3[i];
                float cd = mm.t_var * dd + mm.r_var * (1.0f - dd * inv_dm);
                sXV[s * 50 + 2 * (21 + i) + 0] = m  * INV2PI;
                sXV[s * 50 + 2 * (21 + i) + 1] = cd * NEGHL2E;
            }
        }
        { // ---- BG core (full cov + contraction, closed form) ----
            float t0 = bgz[(NS + 1) * n + s];
            float t1 = bgz[(NS + 1) * n + s + 1];
            Moments mm = frustum_moments(t0, t1, rad);
            float x0 = ox + dx * mm.t_mean;
            float x1 = oy + dy * mm.t_mean;
            float x2 = oz + dz * mm.t_mean;
            float a  = mm.t_var - mm.r_var * inv_dm;   // C = a*ddT + rv*I
            float rv = mm.r_var;
            float rn2 = x0 * x0 + x1 * x1 + x2 * x2;
            float rn  = sqrtf(rn2);
            float nn  = rn + 1e-6f;
            float inn = 1.0f / nn;
            float g   = (2.0f * nn - 1.0f) * inn * inn;       // (2 - 1/n)/n
            float gp  = 2.0f * (1.0f - nn) * inn * inn * inn; // g'(n)
            float h   = gp / rn;                              // J = g*I + h*x*xT
            float xd  = x0 * dx + x1 * dy + x2 * dz;
            float hxd = h * xd;
            float u0 = g * dx + hxd * x0;                     // u = J d
            float u1 = g * dy + hxd * x1;
            float u2 = g * dz + hxd * x2;
            float w  = 2.0f * g * h + h * h * rn2;            // J^2 = g^2 I + w x xT
            float* cr = &sCore[s * 11];
            cr[0] = x0; cr[1] = x1; cr[2] = x2;
            cr[3] = u0; cr[4] = u1; cr[5] = u2;
            cr[6] = g;  cr[7] = a;  cr[8] = rv * g * g; cr[9] = rv * w;
        }
    }
    __syncthreads();

    // ---- BG projections onto 21 basis columns (k wave-uniform, s = lane) ----
    #pragma unroll
    for (int j = 0; j < 6; ++j) {
        int i = tid + 256 * j;
        if (i < 21 * NS) {
            int k = i >> 6;        // wave-uniform
            int s = i & (NS - 1);  // = lane
            const float p0 = c_P[k], p1 = c_P[21 + k], p2 = c_P[42 + k];
            const float* cr = &sCore[s * 11];
            float x0 = cr[0], x1 = cr[1], x2 = cr[2];
            float u0 = cr[3], u1 = cr[4], u2 = cr[5];
            float g = cr[6], c1 = cr[7], c2 = cr[8], c3 = cr[9];
            float dpx = p0 * x0 + p1 * x1 + p2 * x2;
            float dpu = p0 * u0 + p1 * u1 + p2 * u2;
            float pp  = p0 * p0 + p1 * p1 + p2 * p2;
            float y   = g * dpx;
            float yv  = c1 * dpu * dpu + c2 * pp + c3 * dpx * dpx;
            sXV[s * 50 + 2 * k + 0] = y  * INV2PI;
            sXV[s * 50 + 2 * k + 1] = yv * NEGHL2E;
        }
    }
    __syncthreads();

    // ---- Emit 64 samples x 768 channels as 12288 fully-coalesced float4 ----
    float4* __restrict__ outv = reinterpret_cast<float4*>(out) + (size_t)n * (NS * 768 / 4);
    for (int it = 0; it < 48; ++it) {
        int idx = tid + 256 * it;       // float4 slot within this ray
        int s   = idx / 192;            // sample (wave-uniform: 192 = 3*64)
        int c   = (idx - s * 192) * 4;  // first scalar channel [0,768)
        int deg, src, srcLo, srcHi;
        float phq;
        if (c < 96) {                   // fg: channels [0,96), srcs 21..23
            int ph = (c >= 48) ? 1 : 0;
            int jj = c - 48 * ph;
            deg = jj / 3;
            src = 21 + (jj - 3 * deg);
            srcLo = 21; srcHi = 24;
            phq = 0.25f * (float)ph;
        } else {                        // bg: channels [96,768), srcs 0..20
            int local = c - 96;
            int ph = (local >= 336) ? 1 : 0;
            int jj = local - 336 * ph;
            deg = jj / 21;
            src = jj - 21 * deg;
            srcLo = 0; srcHi = 21;
            phq = 0.25f * (float)ph;
        }
        const float* rowXV = &sXV[s * 50];
        float vals[4];
        #pragma unroll
        for (int q = 0; q < 4; ++q) {
            float X = rowXV[2 * src + 0];
            float V = rowXV[2 * src + 1];
            float sf  = __int_as_float((127 + deg) << 23);      // 2^deg
            float s2f = __int_as_float((127 + 2 * deg) << 23);  // 4^deg
            float e = __builtin_amdgcn_exp2f(V * s2f);          // exp(-0.5*var*4^deg)
            float r = __builtin_amdgcn_fractf(X * sf + phq);    // revolutions in [0,1)
            vals[q] = e * __builtin_amdgcn_sinf(r);             // sin(2*pi*r)
            if (++src == srcHi) { src = srcLo; ++deg; }
        }
        outv[idx] = make_float4(vals[0], vals[1], vals[2], vals[3]);
    }
}

extern "C" void kernel_launch(void* const* d_in, const int* in_sizes, int n_in,
                              void* d_out, int out_size, void* d_ws, size_t ws_size,
                              hipStream_t stream) {
    const float* ray_o = (const float*)d_in[0];
    const float* ray_d = (const float*)d_in[1];
    const float* fgz   = (const float*)d_in[2];
    const float* bgz   = (const float*)d_in[3];
    const float* radii = (const float*)d_in[4];
    float* out = (float*)d_out;
    const int N = in_sizes[0] / 3;   // 2048 rays
    mipnerf_enc<<<N, 256, 0, stream>>>(ray_o, ray_d, fgz, bgz, radii, out);
}